// Round 5
// baseline (3710.934 us; speedup 1.0000x reference)
//
#include <hip/hip_runtime.h>
#include <cmath>

#define TSEQ 4096
#define NB   32
#define DIM  256

typedef float f2v __attribute__((ext_vector_type(2)));
typedef float f4v __attribute__((ext_vector_type(4)));

__device__ __forceinline__ f2v fma2(f2v a, f2v b, f2v c) {
    return __builtin_elementwise_fma(a, b, c);   // v_pk_fma_f32 on CDNA
}
__device__ __forceinline__ f2v lo2(f4v v) { return __builtin_shufflevector(v, v, 0, 1); }
__device__ __forceinline__ f2v hi2(f4v v) { return __builtin_shufflevector(v, v, 2, 3); }

// ---------------------------------------------------------------------------
// K1: out[r,:] = X[b,t,:] @ Wx^T + (Wx_b + Wh_b), where r = t*32 + b
// BM=64, BN=64, BK=32; 256 threads; 4x4 micro-tile via packed f32 FMA.
// ---------------------------------------------------------------------------
__global__ __launch_bounds__(256) void k1_xproj(
    const float* __restrict__ X, const float* __restrict__ Wx,
    const float* __restrict__ bx, const float* __restrict__ bh,
    float* __restrict__ out)
{
    __shared__ __align__(16) float As[32][68];
    __shared__ __align__(16) float Bs[32][68];
    const int tid = threadIdx.x;
    const int r0 = blockIdx.x * 64;
    const int n0 = blockIdx.y * 64;
    const int tm = tid >> 4, tn = tid & 15;
    const int lr = tid >> 2;
    const int lk = (tid & 3) * 8;

    const int rg = r0 + lr;
    const float* arow = X + ((size_t)(rg & 31) * TSEQ + (size_t)(rg >> 5)) * DIM;
    const float* brow = Wx + (size_t)(n0 + lr) * DIM;

    f2v acc2[4][2] = {};

    for (int k0 = 0; k0 < DIM; k0 += 32) {
        float4 a0 = *(const float4*)(arow + k0 + lk);
        float4 a1 = *(const float4*)(arow + k0 + lk + 4);
        float4 b0 = *(const float4*)(brow + k0 + lk);
        float4 b1 = *(const float4*)(brow + k0 + lk + 4);
        __syncthreads();
        As[lk+0][lr]=a0.x; As[lk+1][lr]=a0.y; As[lk+2][lr]=a0.z; As[lk+3][lr]=a0.w;
        As[lk+4][lr]=a1.x; As[lk+5][lr]=a1.y; As[lk+6][lr]=a1.z; As[lk+7][lr]=a1.w;
        Bs[lk+0][lr]=b0.x; Bs[lk+1][lr]=b0.y; Bs[lk+2][lr]=b0.z; Bs[lk+3][lr]=b0.w;
        Bs[lk+4][lr]=b1.x; Bs[lk+5][lr]=b1.y; Bs[lk+6][lr]=b1.z; Bs[lk+7][lr]=b1.w;
        __syncthreads();
        #pragma unroll
        for (int k = 0; k < 32; ++k) {
            f4v av = *(const f4v*)&As[k][4*tm];
            f4v bv = *(const f4v*)&Bs[k][4*tn];
            f2v b01 = lo2(bv), b23 = hi2(bv);
            #pragma unroll
            for (int i = 0; i < 4; ++i) {
                f2v ai = {av[i], av[i]};
                acc2[i][0] = fma2(ai, b01, acc2[i][0]);
                acc2[i][1] = fma2(ai, b23, acc2[i][1]);
            }
        }
    }

    float4 bxa = *(const float4*)(bx + n0 + 4*tn);
    float4 bha = *(const float4*)(bh + n0 + 4*tn);
    float bias[4] = {bxa.x + bha.x, bxa.y + bha.y, bxa.z + bha.z, bxa.w + bha.w};
    #pragma unroll
    for (int i = 0; i < 4; ++i) {
        size_t r = (size_t)(r0 + 4*tm + i);
        float4 o = make_float4(acc2[i][0].x + bias[0], acc2[i][0].y + bias[1],
                               acc2[i][1].x + bias[2], acc2[i][1].y + bias[3]);
        *(float4*)(out + r*DIM + n0 + 4*tn) = o;
    }
}

// ---------------------------------------------------------------------------
// K2: sequential recurrence, in-place on d_out.
// 1024 threads = 16 waves (4/SIMD). Thread (s,j): s=tid>>8 (k-quarter,
// wave-uniform), j=tid&255 (output row). 64 weights/thread as 32 f2v pairs
// (64 VGPRs, fits the 128-VGPR cap of launch_bounds(1024,4)).
// Matvec: 16 ds_read_b128 (wave-uniform broadcast) + 32 v_pk_fma_f32 per
// thread per step. s=1..3 publish partials; s=0 reduces + tanh + writes h.
// Raw lgkmcnt-only barriers keep xp-prefetch/h-store vmem off the
// critical path. Branch-free tanh via exp2+rcp.
// ---------------------------------------------------------------------------
__global__ __launch_bounds__(1024, 4) void k2_rnn(
    const float* __restrict__ Wh, float* __restrict__ XH)
{
    const int b = blockIdx.x;
    const int tid = threadIdx.x;
    const int j = tid & 255;
    const int s = tid >> 8;          // k-quarter: 0..3 (wave-uniform)

    __shared__ __align__(16) float hs[256];
    __shared__ __align__(16) float part[3][256];

    // Wh[j][64*s .. 64*s+63] -> 32 f2v pairs
    f2v w2[32];
    {
        const float* wb = Wh + (size_t)j * DIM + 64 * s;
        #pragma unroll
        for (int kk = 0; kk < 64; kk += 4) {
            f4v v = *(const f4v*)(wb + kk);
            w2[kk/2]     = lo2(v);
            w2[kk/2 + 1] = hi2(v);
        }
    }

    if (s == 0) hs[j] = 0.0f;
    float xp_cur = 0.0f;
    if (s == 0) xp_cur = XH[(size_t)b * DIM + j];      // row t=0
    asm volatile("s_waitcnt lgkmcnt(0)\n\ts_barrier" ::: "memory");

    const float* hbase = &hs[64 * s];

    for (int t = 0; t < TSEQ; ++t) {
        const int t1 = (t + 1 < TSEQ) ? (t + 1) : t;
        float xp_nxt = 0.0f;
        if (s == 0) xp_nxt = XH[((size_t)t1 * NB + b) * DIM + j];  // prefetch

        f2v acc0 = {0.f, 0.f}, acc1 = {0.f, 0.f};
        #pragma unroll
        for (int kk = 0; kk < 64; kk += 8) {
            f4v h0 = *(const f4v*)(hbase + kk);
            f4v h1 = *(const f4v*)(hbase + kk + 4);
            acc0 = fma2(w2[kk/2 + 0], lo2(h0), acc0);
            acc1 = fma2(w2[kk/2 + 1], hi2(h0), acc1);
            acc0 = fma2(w2[kk/2 + 2], lo2(h1), acc0);
            acc1 = fma2(w2[kk/2 + 3], hi2(h1), acc1);
        }
        float acc = (acc0.x + acc1.x) + (acc0.y + acc1.y);

        if (s) part[s-1][j] = acc;   // s=1..3 publish partials
        asm volatile("s_waitcnt lgkmcnt(0)\n\ts_barrier" ::: "memory");

        if (s == 0) {
            float sum = ((acc + part[0][j]) + (part[1][j] + part[2][j])) + xp_cur;
            // tanh(x) = 1 - 2/(exp(2x)+1); exp via v_exp_f32 (2^x), rcp raw.
            float e = __builtin_amdgcn_exp2f(sum * 2.8853900817779268f); // 2*log2(e)
            float r = __builtin_amdgcn_rcpf(e + 1.0f);
            float hn = fmaf(-2.0f, r, 1.0f);
            hs[j] = hn;
            XH[((size_t)t * NB + b) * DIM + j] = hn;   // fire-and-forget
        }
        xp_cur = xp_nxt;
        asm volatile("s_waitcnt lgkmcnt(0)\n\ts_barrier" ::: "memory");
    }
}

// ---------------------------------------------------------------------------
// K3: in-place y = h @ Wy^T + Wy_b on d_out (row-exclusive tiles: WG owns
// 64 full rows, all A reads precede the barrier preceding any C write).
// ---------------------------------------------------------------------------
__global__ __launch_bounds__(256) void k3_y(
    const float* __restrict__ Wy, const float* __restrict__ by,
    float* __restrict__ XH)
{
    __shared__ __align__(16) float As[32][68];
    __shared__ __align__(16) float Bs[32][264];
    const int tid = threadIdx.x;
    const int r0 = blockIdx.x * 64;
    const int tm = tid >> 4, tn = tid & 15;
    const int lr = tid >> 2;
    const int lk = (tid & 3) * 8;

    const float* arow = XH + (size_t)(r0 + lr) * DIM;
    const float* brow = Wy + (size_t)tid * DIM;

    f2v acc2[4][4][2] = {};   // [row i][colgroup c][pair]

    for (int k0 = 0; k0 < DIM; k0 += 32) {
        float4 a0 = *(const float4*)(arow + k0 + lk);
        float4 a1 = *(const float4*)(arow + k0 + lk + 4);
        float4 wv[8];
        #pragma unroll
        for (int i = 0; i < 8; ++i) wv[i] = *(const float4*)(brow + k0 + 4*i);
        __syncthreads();
        As[lk+0][lr]=a0.x; As[lk+1][lr]=a0.y; As[lk+2][lr]=a0.z; As[lk+3][lr]=a0.w;
        As[lk+4][lr]=a1.x; As[lk+5][lr]=a1.y; As[lk+6][lr]=a1.z; As[lk+7][lr]=a1.w;
        #pragma unroll
        for (int i = 0; i < 8; ++i) {
            Bs[4*i+0][tid] = wv[i].x;
            Bs[4*i+1][tid] = wv[i].y;
            Bs[4*i+2][tid] = wv[i].z;
            Bs[4*i+3][tid] = wv[i].w;
        }
        __syncthreads();
        #pragma unroll
        for (int k = 0; k < 32; ++k) {
            f4v av = *(const f4v*)&As[k][4*tm];
            #pragma unroll
            for (int c = 0; c < 4; ++c) {
                f4v bv = *(const f4v*)&Bs[k][64*c + 4*tn];
                f2v b01 = lo2(bv), b23 = hi2(bv);
                #pragma unroll
                for (int i = 0; i < 4; ++i) {
                    f2v ai = {av[i], av[i]};
                    acc2[i][c][0] = fma2(ai, b01, acc2[i][c][0]);
                    acc2[i][c][1] = fma2(ai, b23, acc2[i][c][1]);
                }
            }
        }
    }

    float4 byv[4];
    #pragma unroll
    for (int c = 0; c < 4; ++c) byv[c] = *(const float4*)(by + 64*c + 4*tn);
    #pragma unroll
    for (int i = 0; i < 4; ++i) {
        size_t r = (size_t)(r0 + 4*tm + i);
        #pragma unroll
        for (int c = 0; c < 4; ++c) {
            float4 o = make_float4(acc2[i][c][0].x + byv[c].x, acc2[i][c][0].y + byv[c].y,
                                   acc2[i][c][1].x + byv[c].z, acc2[i][c][1].y + byv[c].w);
            *(float4*)(XH + r*DIM + 64*c + 4*tn) = o;
        }
    }
}

extern "C" void kernel_launch(void* const* d_in, const int* in_sizes, int n_in,
                              void* d_out, int out_size, void* d_ws, size_t ws_size,
                              hipStream_t stream)
{
    const float* X    = (const float*)d_in[0];
    const float* Wx_w = (const float*)d_in[1];
    const float* Wx_b = (const float*)d_in[2];
    const float* Wh_w = (const float*)d_in[3];
    const float* Wh_b = (const float*)d_in[4];
    const float* Wy_w = (const float*)d_in[5];
    const float* Wy_b = (const float*)d_in[6];
    float* out = (float*)d_out;

    dim3 g1((TSEQ * NB) / 64, DIM / 64);
    k1_xproj<<<g1, 256, 0, stream>>>(X, Wx_w, Wx_b, Wh_b, out);

    k2_rnn<<<NB, 1024, 0, stream>>>(Wh_w, out);

    k3_y<<<(TSEQ * NB) / 64, 256, 0, stream>>>(Wy_w, Wy_b, out);
}